// Round 4
// baseline (271.851 us; speedup 1.0000x reference)
//
#include <hip/hip_runtime.h>

#define ROWS 1024
#define COLS 1024
#define NN (ROWS*COLS)

// R9: wave-autonomous 32x32 regions, barrier-free (fixed geometry).
// 8x8 lane grid x 4x4 cells/lane = 1024 cells/wave, output central 16x16.
// Per Jacobi step: 16 __shfl (ds_bpermute) + 64 FMA per lane. No LDS,
// no __syncthreads -- waves free-run, stalls uncorrelated.
#define OT    16               // output tile per wave
#define HALO  8
#define RS    32               // region = OT + 2*HALO
#define TPD   (COLS/OT)        // 64 tiles per dimension
#define NWAVE (TPD*TPD)        // 4096 waves per launch
#define WPB   4                // waves per block
#define NT    (WPB*64)         // 256 threads
#define NBLK  (NWAVE/WPB)      // 1024 blocks

static constexpr float RHOG    = 1000.0f * 9.81f;
static constexpr float INV_SEC = 1.0f / 31556926.0f;
static constexpr float FLOWC   = 0.0405f;

__device__ __forceinline__ float4 gld4(const float* __restrict__ p, int g, bool in) {
    if (in) return *reinterpret_cast<const float4*>(p + g);
    return make_float4(0.f, 0.f, 0.f, 0.f);
}

// ---- prologue: phi, inv_total, runoff -------------------------------------
__global__ __launch_bounds__(256) void k_pre(
        const float* __restrict__ bed, const float* __restrict__ pw,
        const int* __restrict__ status,
        const float* __restrict__ melt, const float* __restrict__ area,
        float* __restrict__ phi, float* __restrict__ inv,
        float* __restrict__ runoff) {
    int i = blockIdx.x * 256 + threadIdx.x;
    int r = i >> 10, c = i & (COLS - 1);
    float p = RHOG * bed[i] + pw[i];
    float t = 0.f;
    if (c > 0)        t += fmaxf(p - (RHOG * bed[i - 1]    + pw[i - 1]),    0.f);
    if (c < COLS - 1) t += fmaxf(p - (RHOG * bed[i + 1]    + pw[i + 1]),    0.f);
    if (r > 0)        t += fmaxf(p - (RHOG * bed[i - COLS] + pw[i - COLS]), 0.f);
    if (r < ROWS - 1) t += fmaxf(p - (RHOG * bed[i + COLS] + pw[i + COLS]), 0.f);
    phi[i]    = p;
    inv[i]    = (status[i] == 0 && t > 0.f) ? (1.f / t) : 0.f;
    runoff[i] = melt[i] * area[i] * INV_SEC;
}

// ---- 8-step register-resident Jacobi, one wave per 32x32 region -----------
template <bool FIRST, bool FINAL>
__global__ __launch_bounds__(NT, 3) void k_step(
        const float* __restrict__ phi_g, const float* __restrict__ inv_g,
        const float* __restrict__ run_g, const float* __restrict__ qin,
        float* __restrict__ qout,
        const float* __restrict__ cond, const int* __restrict__ status) {
    const int tid  = threadIdx.x;
    const int lane = tid & 63;
    const int wid  = blockIdx.x * WPB + (tid >> 6);
    const int tr = wid >> 6, tc = wid & (TPD - 1);
    const int R0 = tr * OT - HALO, C0 = tc * OT - HALO;
    const int wr = lane >> 3, wc = lane & 7;            // 8 x 8 lane grid
    const int gr0 = R0 + wr * 4, gc0 = C0 + wc * 4;     // lane's 4x4 block

    // clamped shuffle sources (rim lanes read self: garbage past depth, fine)
    const int upL = (wr > 0) ? lane - 8 : lane;
    const int dnL = (wr < 7) ? lane + 8 : lane;
    const int lfL = (wc > 0) ? lane - 1 : lane;
    const int rtL = (wc < 7) ? lane + 1 : lane;

    const bool cin = ((unsigned)gc0 < COLS);
    bool in[4];
    int  g[4];
#pragma unroll
    for (int i = 0; i < 4; ++i) {
        in[i] = ((unsigned)(gr0 + i) < ROWS) & cin;
        g[i]  = (gr0 + i) * COLS + gc0;
    }

    // ---- stage phi/inv for this lane's 4x4 cells --------------------------
    float ph[4][4], iv[4][4];
#pragma unroll
    for (int i = 0; i < 4; ++i) {
        float4 p4 = gld4(phi_g, g[i], in[i]);
        float4 i4 = gld4(inv_g, g[i], in[i]);
        ph[i][0]=p4.x; ph[i][1]=p4.y; ph[i][2]=p4.z; ph[i][3]=p4.w;
        iv[i][0]=i4.x; iv[i][1]=i4.y; iv[i][2]=i4.z; iv[i][3]=i4.w;
    }

    // halo phi/inv via shuffles (32 ops, setup only)
    float phU[4], phD[4], ivU[4], ivD[4], phL[4], phR[4], ivL[4], ivR[4];
#pragma unroll
    for (int j = 0; j < 4; ++j) {
        phU[j] = __shfl(ph[3][j], upL, 64);  ivU[j] = __shfl(iv[3][j], upL, 64);
        phD[j] = __shfl(ph[0][j], dnL, 64);  ivD[j] = __shfl(iv[0][j], dnL, 64);
    }
#pragma unroll
    for (int i = 0; i < 4; ++i) {
        phL[i] = __shfl(ph[i][3], lfL, 64);  ivL[i] = __shfl(iv[i][3], lfL, 64);
        phR[i] = __shfl(ph[i][0], rtL, 64);  ivR[i] = __shfl(iv[i][0], rtL, 64);
    }

    // ---- weights into registers (ph/iv die here) --------------------------
    float wW[4][4], wE[4][4], wN[4][4], wS[4][4];
#pragma unroll
    for (int i = 0; i < 4; ++i)
#pragma unroll
        for (int j = 0; j < 4; ++j) {
            float pc = ph[i][j];
            float pu = (i > 0) ? ph[i-1][j] : phU[j];
            float iu = (i > 0) ? iv[i-1][j] : ivU[j];
            float pd = (i < 3) ? ph[i+1][j] : phD[j];
            float id = (i < 3) ? iv[i+1][j] : ivD[j];
            float pl = (j > 0) ? ph[i][j-1] : phL[i];
            float il = (j > 0) ? iv[i][j-1] : ivL[i];
            float pr = (j < 3) ? ph[i][j+1] : phR[i];
            float ir = (j < 3) ? iv[i][j+1] : ivR[i];
            wN[i][j] = fmaxf(pu - pc, 0.f) * iu;
            wS[i][j] = fmaxf(pd - pc, 0.f) * id;
            wW[i][j] = fmaxf(pl - pc, 0.f) * il;
            wE[i][j] = fmaxf(pr - pc, 0.f) * ir;
        }

    // ---- runoff + q0 ------------------------------------------------------
    float q[4][4], ro[4][4];
#pragma unroll
    for (int i = 0; i < 4; ++i) {
        float4 r4 = gld4(run_g, g[i], in[i]);
        ro[i][0]=r4.x; ro[i][1]=r4.y; ro[i][2]=r4.z; ro[i][3]=r4.w;
        if (FIRST) {
            q[i][0]=r4.x; q[i][1]=r4.y; q[i][2]=r4.z; q[i][3]=r4.w;
        } else {
            float4 q4 = gld4(qin, g[i], in[i]);
            q[i][0]=q4.x; q[i][1]=q4.y; q[i][2]=q4.z; q[i][3]=q4.w;
        }
    }

    // ---- 8 Jacobi steps: 16 shuffles + 64 FMA per lane, no barriers -------
#pragma unroll
    for (int s = 0; s < HALO; ++s) {
        float u[4], d[4], l[4], r[4];
#pragma unroll
        for (int j = 0; j < 4; ++j) {
            u[j] = __shfl(q[3][j], upL, 64);
            d[j] = __shfl(q[0][j], dnL, 64);
        }
#pragma unroll
        for (int i = 0; i < 4; ++i) {
            l[i] = __shfl(q[i][3], lfL, 64);
            r[i] = __shfl(q[i][0], rtL, 64);
        }
        float nq[4][4];
#pragma unroll
        for (int i = 0; i < 4; ++i)
#pragma unroll
            for (int j = 0; j < 4; ++j) {
                float uv = (i > 0) ? q[i-1][j] : u[j];
                float dv = (i < 3) ? q[i+1][j] : d[j];
                float lv = (j > 0) ? q[i][j-1] : l[i];
                float rv = (j < 3) ? q[i][j+1] : r[i];
                float a = ro[i][j];
                a = fmaf(wW[i][j], lv, a);
                a = fmaf(wE[i][j], rv, a);
                a = fmaf(wN[i][j], uv, a);
                a = fmaf(wS[i][j], dv, a);
                nq[i][j] = a;
            }
#pragma unroll
        for (int i = 0; i < 4; ++i)
#pragma unroll
            for (int j = 0; j < 4; ++j) q[i][j] = nq[i][j];
    }

    // ---- write the central 16x16 (lanes wr,wc in [2,6)) -------------------
    if ((wr >= 2) & (wr < 6) & (wc >= 2) & (wc < 6)) {
#pragma unroll
        for (int i = 0; i < 4; ++i) {
            int go = g[i];                        // always in-grid here
            if (FINAL) {
                float4 c4 = *reinterpret_cast<const float4*>(cond + go);
                int4 st   = *reinterpret_cast<const int4*>(status + go);
                float4 o;
                float t;
                t = q[i][0] * FLOWC * (c4.x * sqrtf(sqrtf(c4.x))); o.x = (st.x == 0) ? t * t : 0.f;
                t = q[i][1] * FLOWC * (c4.y * sqrtf(sqrtf(c4.y))); o.y = (st.y == 0) ? t * t : 0.f;
                t = q[i][2] * FLOWC * (c4.z * sqrtf(sqrtf(c4.z))); o.z = (st.z == 0) ? t * t : 0.f;
                t = q[i][3] * FLOWC * (c4.w * sqrtf(sqrtf(c4.w))); o.w = (st.w == 0) ? t * t : 0.f;
                *reinterpret_cast<float4*>(qout + go) = o;
            } else {
                *reinterpret_cast<float4*>(qout + go) =
                    make_float4(q[i][0], q[i][1], q[i][2], q[i][3]);
            }
        }
    }
}

extern "C" void kernel_launch(void* const* d_in, const int* in_sizes, int n_in,
                              void* d_out, int out_size, void* d_ws, size_t ws_size,
                              hipStream_t stream) {
    const float* melt   = (const float*)d_in[0];
    const float* bed    = (const float*)d_in[1];
    const float* pw     = (const float*)d_in[2];
    const float* area   = (const float*)d_in[3];
    const float* cond   = (const float*)d_in[4];
    const int*   status = (const int*)d_in[5];
    float* out = (float*)d_out;

    char* ws = (char*)d_ws;
    float* phi    = (float*)(ws);                 //  4 MB
    float* inv    = (float*)(ws + 4ull  * NN);    //  4 MB
    float* runoff = (float*)(ws + 8ull  * NN);    //  4 MB
    float* qA     = (float*)(ws + 12ull * NN);    //  4 MB
    float* qB     = (float*)(ws + 16ull * NN);    //  4 MB (20 MB total)

    k_pre<<<dim3(NN / 256), dim3(256), 0, stream>>>(bed, pw, status, melt, area,
                                                    phi, inv, runoff);

    dim3 grid(NBLK), block(NT);
    k_step<true,  false><<<grid, block, 0, stream>>>(phi, inv, runoff, runoff, qA, nullptr, nullptr);
    k_step<false, false><<<grid, block, 0, stream>>>(phi, inv, runoff, qA, qB, nullptr, nullptr);
    k_step<false, false><<<grid, block, 0, stream>>>(phi, inv, runoff, qB, qA, nullptr, nullptr);
    k_step<false, true ><<<grid, block, 0, stream>>>(phi, inv, runoff, qA, out, cond, status);
}